// Round 1
// baseline (3505.378 us; speedup 1.0000x reference)
//
#include <hip/hip_runtime.h>

// GraphSAGE 3-layer forward, fp32 baseline.
// Pipeline per layer L (in = H, width K=128):
//   1. neigh GEMM:  B  = relu?(H) @ W_n          (N x NCOL)
//   2. self  GEMM:  A  = relu?(H) @ W_s + b      (A = H in-place for L1, d_out for L2)
//   3. scatter:     A[dst] += B[src] * inv_deg[dst]   (fp32 atomics)
// ReLU is applied on LOAD by the next layer's GEMMs (layers 1,2), never stored.
// inv_deg computed once per call (memset + atomic count + reciprocal).

#define NN 100000
#define NE 1600000

__device__ inline float4 relu4f(float4 v) {
    v.x = fmaxf(v.x, 0.f); v.y = fmaxf(v.y, 0.f);
    v.z = fmaxf(v.z, 0.f); v.w = fmaxf(v.w, 0.f);
    return v;
}

// GEMM: out[M x NCOL] = act(in[M x 128]) @ W[128 x NCOL] (+ bias)
// Block: 256 threads, 32 rows. W fully staged in LDS (64KB for NCOL=128 -> 2 blocks/CU).
// Thread tile: RPT rows x 4 cols. h loads are wave-broadcast (all lanes same addr).
// In-place (out==in) is safe: row i's output depends only on row i's input, and all
// readers/writers of a given row are lanes of one lockstep wave (reads precede writes).
template<int NCOL, bool RELU_IN, bool BIAS>
__global__ __launch_bounds__(256) void gemm_k(
    const float* in, const float* __restrict__ W,
    const float* __restrict__ bias, float* out)
{
    constexpr int K = 128;
    constexpr int QUADS = NCOL / 4;   // 32 or 16
    constexpr int G = 256 / QUADS;    // 8 or 16 row-groups
    constexpr int RPB = 32;           // rows per block (100000 % 32 == 0)
    constexpr int RPT = RPB / G;      // 4 or 2 rows per thread

    __shared__ float Wlds[K * NCOL];
    {
        const float4* Wg = reinterpret_cast<const float4*>(W);
        float4* Wl = reinterpret_cast<float4*>(Wlds);
        #pragma unroll
        for (int i = 0; i < K * NCOL / 4 / 256; ++i)
            Wl[threadIdx.x + i * 256] = Wg[threadIdx.x + i * 256];
    }
    __syncthreads();

    const int tx = threadIdx.x % QUADS;
    const int ty = threadIdx.x / QUADS;
    const int row0 = blockIdx.x * RPB;

    const float* rp[RPT];
    #pragma unroll
    for (int i = 0; i < RPT; ++i)
        rp[i] = in + (size_t)(row0 + ty + i * G) * K;

    float acc[RPT][4];
    #pragma unroll
    for (int i = 0; i < RPT; ++i)
        acc[i][0] = acc[i][1] = acc[i][2] = acc[i][3] = 0.f;

    #pragma unroll 2
    for (int kc = 0; kc < K; kc += 4) {
        float4 h4[RPT];
        #pragma unroll
        for (int i = 0; i < RPT; ++i) {
            h4[i] = *reinterpret_cast<const float4*>(rp[i] + kc);
            if (RELU_IN) h4[i] = relu4f(h4[i]);
        }
        #pragma unroll
        for (int kk = 0; kk < 4; ++kk) {
            const float4 w4 = *reinterpret_cast<const float4*>(&Wlds[(kc + kk) * NCOL + tx * 4]);
            #pragma unroll
            for (int i = 0; i < RPT; ++i) {
                const float hv = (&h4[i].x)[kk];
                acc[i][0] = fmaf(hv, w4.x, acc[i][0]);
                acc[i][1] = fmaf(hv, w4.y, acc[i][1]);
                acc[i][2] = fmaf(hv, w4.z, acc[i][2]);
                acc[i][3] = fmaf(hv, w4.w, acc[i][3]);
            }
        }
    }

    float4 b4 = make_float4(0.f, 0.f, 0.f, 0.f);
    if (BIAS) b4 = *reinterpret_cast<const float4*>(&bias[tx * 4]);
    #pragma unroll
    for (int i = 0; i < RPT; ++i) {
        const int r = row0 + ty + i * G;
        float4 o;
        o.x = acc[i][0] + b4.x; o.y = acc[i][1] + b4.y;
        o.z = acc[i][2] + b4.z; o.w = acc[i][3] + b4.w;
        *reinterpret_cast<float4*>(&out[(size_t)r * NCOL + tx * 4]) = o;
    }
}

__global__ void deg_k(const int* __restrict__ dst, float* __restrict__ deg, int E) {
    const int i = blockIdx.x * blockDim.x + threadIdx.x;
    if (i < E) atomicAdd(&deg[dst[i]], 1.0f);
}

__global__ void inv_k(float* deg, int n) {
    const int i = blockIdx.x * blockDim.x + threadIdx.x;
    if (i < n) deg[i] = 1.0f / fmaxf(deg[i], 1.0f);
}

// One wave per edge (grid-stride). Lanes cover the feature dim.
__global__ __launch_bounds__(256) void scatter128_k(
    const int* __restrict__ src, const int* __restrict__ dst,
    const float* __restrict__ inv, const float* __restrict__ B,
    float* A, int E)
{
    const int lane = threadIdx.x & 63;
    int w = (blockIdx.x * 256 + threadIdx.x) >> 6;
    const int nw = (gridDim.x * 256) >> 6;
    for (int e = w; e < E; e += nw) {
        const int s = src[e];
        const int d = dst[e];
        const float sc = inv[d];
        const float2 v = *reinterpret_cast<const float2*>(&B[(size_t)s * 128 + lane * 2]);
        atomicAdd(&A[(size_t)d * 128 + lane * 2    ], v.x * sc);
        atomicAdd(&A[(size_t)d * 128 + lane * 2 + 1], v.y * sc);
    }
}

__global__ __launch_bounds__(256) void scatter64_k(
    const int* __restrict__ src, const int* __restrict__ dst,
    const float* __restrict__ inv, const float* __restrict__ B,
    float* A, int E)
{
    const int lane = threadIdx.x & 63;
    int w = (blockIdx.x * 256 + threadIdx.x) >> 6;
    const int nw = (gridDim.x * 256) >> 6;
    for (int e = w; e < E; e += nw) {
        const int s = src[e];
        const int d = dst[e];
        const float sc = inv[d];
        const float v = B[(size_t)s * 64 + lane];
        atomicAdd(&A[(size_t)d * 64 + lane], v * sc);
    }
}

extern "C" void kernel_launch(void* const* d_in, const int* in_sizes, int n_in,
                              void* d_out, int out_size, void* d_ws, size_t ws_size,
                              hipStream_t stream) {
    const float* x   = (const float*)d_in[0];
    const int*   src = (const int*)  d_in[1];
    const int*   dst = (const int*)  d_in[2];
    const float* ws0 = (const float*)d_in[3];
    const float* wn0 = (const float*)d_in[4];
    const float* b0  = (const float*)d_in[5];
    const float* ws1 = (const float*)d_in[6];
    const float* wn1 = (const float*)d_in[7];
    const float* b1  = (const float*)d_in[8];
    const float* ws2 = (const float*)d_in[9];
    const float* wn2 = (const float*)d_in[10];
    const float* b2  = (const float*)d_in[11];
    float* out = (float*)d_out;

    // workspace layout: [inv_deg: 400KB][pad to 1MB][H0: 51.2MB][B: 51.2MB]
    float* inv = (float*)d_ws;
    float* H0  = (float*)((char*)d_ws + (1u << 20));
    float* Bf  = H0 + (size_t)NN * 128;

    const int GEMM_BLOCKS = NN / 32;  // 3125, exact
    const int SC_BLOCKS = 4096;

    // degree -> inverse degree (in place)
    hipMemsetAsync(inv, 0, NN * sizeof(float), stream);
    deg_k<<<(NE + 255) / 256, 256, 0, stream>>>(dst, inv, NE);
    inv_k<<<(NN + 255) / 256, 256, 0, stream>>>(inv, NN);

    // Layer 0 (input x, no relu)
    gemm_k<128, false, false><<<GEMM_BLOCKS, 256, 0, stream>>>(x, wn0, nullptr, Bf);
    gemm_k<128, false, true ><<<GEMM_BLOCKS, 256, 0, stream>>>(x, ws0, b0, H0);
    scatter128_k<<<SC_BLOCKS, 256, 0, stream>>>(src, dst, inv, Bf, H0, NE);

    // Layer 1 (input relu(H0); self GEMM in-place)
    gemm_k<128, true, false><<<GEMM_BLOCKS, 256, 0, stream>>>(H0, wn1, nullptr, Bf);
    gemm_k<128, true, true ><<<GEMM_BLOCKS, 256, 0, stream>>>(H0, ws1, b1, H0);
    scatter128_k<<<SC_BLOCKS, 256, 0, stream>>>(src, dst, inv, Bf, H0, NE);

    // Layer 2 (input relu(H0), output 64 wide, no relu on output)
    gemm_k<64, true, false><<<GEMM_BLOCKS, 256, 0, stream>>>(H0, wn2, nullptr, Bf);
    gemm_k<64, true, true ><<<GEMM_BLOCKS, 256, 0, stream>>>(H0, ws2, b2, out);
    scatter64_k<<<SC_BLOCKS, 256, 0, stream>>>(src, dst, inv, Bf, out, NE);
}

// Round 2
// 982.420 us; speedup vs baseline: 3.5681x; 3.5681x over previous
//
#include <hip/hip_runtime.h>

// GraphSAGE 3-layer forward, fp32.
// R2: atomic scatter replaced by CSR(by-dst) build + gather aggregation.
// Per layer: B = relu?(H) @ W_n ; A = relu?(H) @ W_s + b ; A[d] += mean_{e:dst=d} B[src[e]]
// ReLU applied on LOAD by next layer's GEMMs. 1/deg from CSR row extents.

#define NN 100000
#define NE 1600000

__device__ inline float4 relu4f(float4 v) {
    v.x = fmaxf(v.x, 0.f); v.y = fmaxf(v.y, 0.f);
    v.z = fmaxf(v.z, 0.f); v.w = fmaxf(v.w, 0.f);
    return v;
}

// ---------------- GEMM (unchanged from R1) ----------------
template<int NCOL, bool RELU_IN, bool BIAS>
__global__ __launch_bounds__(256) void gemm_k(
    const float* in, const float* __restrict__ W,
    const float* __restrict__ bias, float* out)
{
    constexpr int K = 128;
    constexpr int QUADS = NCOL / 4;
    constexpr int G = 256 / QUADS;
    constexpr int RPB = 32;
    constexpr int RPT = RPB / G;

    __shared__ float Wlds[K * NCOL];
    {
        const float4* Wg = reinterpret_cast<const float4*>(W);
        float4* Wl = reinterpret_cast<float4*>(Wlds);
        #pragma unroll
        for (int i = 0; i < K * NCOL / 4 / 256; ++i)
            Wl[threadIdx.x + i * 256] = Wg[threadIdx.x + i * 256];
    }
    __syncthreads();

    const int tx = threadIdx.x % QUADS;
    const int ty = threadIdx.x / QUADS;
    const int row0 = blockIdx.x * RPB;

    const float* rp[RPT];
    #pragma unroll
    for (int i = 0; i < RPT; ++i)
        rp[i] = in + (size_t)(row0 + ty + i * G) * K;

    float acc[RPT][4];
    #pragma unroll
    for (int i = 0; i < RPT; ++i)
        acc[i][0] = acc[i][1] = acc[i][2] = acc[i][3] = 0.f;

    #pragma unroll 2
    for (int kc = 0; kc < K; kc += 4) {
        float4 h4[RPT];
        #pragma unroll
        for (int i = 0; i < RPT; ++i) {
            h4[i] = *reinterpret_cast<const float4*>(rp[i] + kc);
            if (RELU_IN) h4[i] = relu4f(h4[i]);
        }
        #pragma unroll
        for (int kk = 0; kk < 4; ++kk) {
            const float4 w4 = *reinterpret_cast<const float4*>(&Wlds[(kc + kk) * NCOL + tx * 4]);
            #pragma unroll
            for (int i = 0; i < RPT; ++i) {
                const float hv = (&h4[i].x)[kk];
                acc[i][0] = fmaf(hv, w4.x, acc[i][0]);
                acc[i][1] = fmaf(hv, w4.y, acc[i][1]);
                acc[i][2] = fmaf(hv, w4.z, acc[i][2]);
                acc[i][3] = fmaf(hv, w4.w, acc[i][3]);
            }
        }
    }

    float4 b4 = make_float4(0.f, 0.f, 0.f, 0.f);
    if (BIAS) b4 = *reinterpret_cast<const float4*>(&bias[tx * 4]);
    #pragma unroll
    for (int i = 0; i < RPT; ++i) {
        const int r = row0 + ty + i * G;
        float4 o;
        o.x = acc[i][0] + b4.x; o.y = acc[i][1] + b4.y;
        o.z = acc[i][2] + b4.z; o.w = acc[i][3] + b4.w;
        *reinterpret_cast<float4*>(&out[(size_t)r * NCOL + tx * 4]) = o;
    }
}

// ---------------- CSR build ----------------
__global__ void hist_k(const int* __restrict__ dst, int* __restrict__ cnt, int E) {
    const int i = blockIdx.x * blockDim.x + threadIdx.x;
    if (i < E) atomicAdd(&cnt[dst[i]], 1);
}

// exclusive scan, stage 1: 98 blocks x 256 thr x 4 elems = 1024/block
__global__ __launch_bounds__(256) void scan1_k(const int* __restrict__ cnt,
                                               int* __restrict__ row, int* __restrict__ blksum) {
    __shared__ int lds[256];
    const int t = threadIdx.x;
    const int base = blockIdx.x * 1024 + t * 4;
    int v[4];
    #pragma unroll
    for (int i = 0; i < 4; ++i) {
        const int idx = base + i;
        v[i] = (idx < NN) ? cnt[idx] : 0;
    }
    const int s = v[0] + v[1] + v[2] + v[3];
    lds[t] = s;
    __syncthreads();
    #pragma unroll
    for (int off = 1; off < 256; off <<= 1) {
        const int cur = lds[t];
        const int y = (t >= off) ? lds[t - off] : 0;
        __syncthreads();
        lds[t] = cur + y;
        __syncthreads();
    }
    const int incl = lds[t];
    if (t == 255) blksum[blockIdx.x] = incl;
    int run = incl - s;  // exclusive
    #pragma unroll
    for (int i = 0; i < 4; ++i) {
        const int idx = base + i;
        if (idx < NN) row[idx] = run;
        run += v[i];
    }
}

// stage 2: single block scans block sums (nb <= 128)
__global__ __launch_bounds__(128) void scan2_k(int* blksum, int nb) {
    __shared__ int lds[128];
    const int t = threadIdx.x;
    const int s = (t < nb) ? blksum[t] : 0;
    lds[t] = s;
    __syncthreads();
    #pragma unroll
    for (int off = 1; off < 128; off <<= 1) {
        const int cur = lds[t];
        const int y = (t >= off) ? lds[t - off] : 0;
        __syncthreads();
        lds[t] = cur + y;
        __syncthreads();
    }
    if (t < nb) blksum[t] = lds[t] - s;  // exclusive
}

// stage 3: add block offsets; also set row[NN] = NE
__global__ __launch_bounds__(256) void scan3_k(int* __restrict__ row, const int* __restrict__ blksum) {
    const int t = threadIdx.x;
    const int add = blksum[blockIdx.x];
    const int base = blockIdx.x * 1024 + t * 4;
    #pragma unroll
    for (int i = 0; i < 4; ++i) {
        const int idx = base + i;
        if (idx < NN) row[idx] += add;
    }
    if (blockIdx.x == 0 && t == 0) row[NN] = NE;
}

// bucket placement; consumes cnt (countdown to 0)
__global__ void place_k(const int* __restrict__ src, const int* __restrict__ dst,
                        const int* __restrict__ row, int* __restrict__ cnt,
                        int* __restrict__ esrc, int E) {
    const int e = blockIdx.x * blockDim.x + threadIdx.x;
    if (e < E) {
        const int d = dst[e];
        const int r = atomicSub(&cnt[d], 1) - 1;
        esrc[row[d] + r] = src[e];
    }
}

// ---------------- gather aggregation: one wave per dst node ----------------
template<int NCOL>
__global__ __launch_bounds__(256) void agg_k(const int* __restrict__ row, const int* __restrict__ esrc,
                                             const float* __restrict__ B, float* A) {
    const int lane = threadIdx.x & 63;
    const int node = (blockIdx.x * 256 + threadIdx.x) >> 6;
    if (node >= NN) return;
    const int e0 = row[node];
    const int e1 = row[node + 1];

    if (NCOL == 128) {
        float2 acc = make_float2(0.f, 0.f);
        int e = e0;
        for (; e + 2 <= e1; e += 2) {
            const int s0 = esrc[e];
            const int s1 = esrc[e + 1];
            const float2 v0 = *reinterpret_cast<const float2*>(&B[(size_t)s0 * 128 + lane * 2]);
            const float2 v1 = *reinterpret_cast<const float2*>(&B[(size_t)s1 * 128 + lane * 2]);
            acc.x += v0.x + v1.x;
            acc.y += v0.y + v1.y;
        }
        if (e < e1) {
            const int s0 = esrc[e];
            const float2 v0 = *reinterpret_cast<const float2*>(&B[(size_t)s0 * 128 + lane * 2]);
            acc.x += v0.x;
            acc.y += v0.y;
        }
        const float invd = (e1 > e0) ? 1.0f / (float)(e1 - e0) : 0.0f;
        float2* ap = reinterpret_cast<float2*>(&A[(size_t)node * 128 + lane * 2]);
        float2 a = *ap;
        a.x += acc.x * invd;
        a.y += acc.y * invd;
        *ap = a;
    } else {
        float acc = 0.f;
        int e = e0;
        for (; e + 2 <= e1; e += 2) {
            const int s0 = esrc[e];
            const int s1 = esrc[e + 1];
            acc += B[(size_t)s0 * 64 + lane] + B[(size_t)s1 * 64 + lane];
        }
        if (e < e1) acc += B[(size_t)esrc[e] * 64 + lane];
        const float invd = (e1 > e0) ? 1.0f / (float)(e1 - e0) : 0.0f;
        A[(size_t)node * 64 + lane] += acc * invd;
    }
}

// ---------------- fallback atomic path (small ws) ----------------
__global__ void deg_k(const int* __restrict__ dst, float* __restrict__ deg, int E) {
    const int i = blockIdx.x * blockDim.x + threadIdx.x;
    if (i < E) atomicAdd(&deg[dst[i]], 1.0f);
}
__global__ void inv_k(float* deg, int n) {
    const int i = blockIdx.x * blockDim.x + threadIdx.x;
    if (i < n) deg[i] = 1.0f / fmaxf(deg[i], 1.0f);
}
__global__ __launch_bounds__(256) void scatter128_k(
    const int* __restrict__ src, const int* __restrict__ dst,
    const float* __restrict__ inv, const float* __restrict__ B, float* A, int E) {
    const int lane = threadIdx.x & 63;
    int w = (blockIdx.x * 256 + threadIdx.x) >> 6;
    const int nw = (gridDim.x * 256) >> 6;
    for (int e = w; e < E; e += nw) {
        const int s = src[e], d = dst[e];
        const float sc = inv[d];
        const float2 v = *reinterpret_cast<const float2*>(&B[(size_t)s * 128 + lane * 2]);
        atomicAdd(&A[(size_t)d * 128 + lane * 2    ], v.x * sc);
        atomicAdd(&A[(size_t)d * 128 + lane * 2 + 1], v.y * sc);
    }
}
__global__ __launch_bounds__(256) void scatter64_k(
    const int* __restrict__ src, const int* __restrict__ dst,
    const float* __restrict__ inv, const float* __restrict__ B, float* A, int E) {
    const int lane = threadIdx.x & 63;
    int w = (blockIdx.x * 256 + threadIdx.x) >> 6;
    const int nw = (gridDim.x * 256) >> 6;
    for (int e = w; e < E; e += nw) {
        const int s = src[e], d = dst[e];
        atomicAdd(&A[(size_t)d * 64 + lane], B[(size_t)s * 64 + lane] * inv[d]);
    }
}

extern "C" void kernel_launch(void* const* d_in, const int* in_sizes, int n_in,
                              void* d_out, int out_size, void* d_ws, size_t ws_size,
                              hipStream_t stream) {
    const float* x   = (const float*)d_in[0];
    const int*   src = (const int*)  d_in[1];
    const int*   dst = (const int*)  d_in[2];
    const float* ws0 = (const float*)d_in[3];
    const float* wn0 = (const float*)d_in[4];
    const float* b0  = (const float*)d_in[5];
    const float* ws1 = (const float*)d_in[6];
    const float* wn1 = (const float*)d_in[7];
    const float* b1  = (const float*)d_in[8];
    const float* ws2 = (const float*)d_in[9];
    const float* wn2 = (const float*)d_in[10];
    const float* b2  = (const float*)d_in[11];
    float* out = (float*)d_out;

    const int GEMM_BLOCKS = NN / 32;               // 3125
    const int NBLK = (NN + 1023) / 1024;           // 98

    // CSR-path workspace layout (bytes):
    // cnt@0 (400K) | row@512K (400K+4) | blksum@1M (512B) | esrc@2M (6.4M) |
    // H0@9M (51.2M) | Bf (51.2M)  => total ~111.9MB
    const size_t NEED = 9u * 1024 * 1024 + 2u * (size_t)NN * 128 * 4;

    if (ws_size >= NEED) {
        int*   cnt  = (int*)d_ws;
        int*   row  = (int*)((char*)d_ws + (512u << 10));
        int*   blks = (int*)((char*)d_ws + (1u << 20));
        int*   esrc = (int*)((char*)d_ws + (2u << 20));
        float* H0   = (float*)((char*)d_ws + (9u << 20));
        float* Bf   = H0 + (size_t)NN * 128;

        // ---- CSR build ----
        hipMemsetAsync(cnt, 0, NN * sizeof(int), stream);
        hist_k<<<(NE + 255) / 256, 256, 0, stream>>>(dst, cnt, NE);
        scan1_k<<<NBLK, 256, 0, stream>>>(cnt, row, blks);
        scan2_k<<<1, 128, 0, stream>>>(blks, NBLK);
        scan3_k<<<NBLK, 256, 0, stream>>>(row, blks);
        place_k<<<(NE + 255) / 256, 256, 0, stream>>>(src, dst, row, cnt, esrc, NE);

        const int AGG_BLOCKS = (NN + 3) / 4;  // 4 waves (nodes) per block

        // Layer 0
        gemm_k<128, false, false><<<GEMM_BLOCKS, 256, 0, stream>>>(x, wn0, nullptr, Bf);
        gemm_k<128, false, true ><<<GEMM_BLOCKS, 256, 0, stream>>>(x, ws0, b0, H0);
        agg_k<128><<<AGG_BLOCKS, 256, 0, stream>>>(row, esrc, Bf, H0);
        // Layer 1
        gemm_k<128, true, false><<<GEMM_BLOCKS, 256, 0, stream>>>(H0, wn1, nullptr, Bf);
        gemm_k<128, true, true ><<<GEMM_BLOCKS, 256, 0, stream>>>(H0, ws1, b1, H0);
        agg_k<128><<<AGG_BLOCKS, 256, 0, stream>>>(row, esrc, Bf, H0);
        // Layer 2
        gemm_k<64, true, false><<<GEMM_BLOCKS, 256, 0, stream>>>(H0, wn2, nullptr, Bf);
        gemm_k<64, true, true ><<<GEMM_BLOCKS, 256, 0, stream>>>(H0, ws2, b2, out);
        agg_k<64><<<AGG_BLOCKS, 256, 0, stream>>>(row, esrc, Bf, out);
    } else {
        // fallback: R1 atomic path
        float* inv = (float*)d_ws;
        float* H0  = (float*)((char*)d_ws + (1u << 20));
        float* Bf  = H0 + (size_t)NN * 128;
        const int SC_BLOCKS = 4096;

        hipMemsetAsync(inv, 0, NN * sizeof(float), stream);
        deg_k<<<(NE + 255) / 256, 256, 0, stream>>>(dst, inv, NE);
        inv_k<<<(NN + 255) / 256, 256, 0, stream>>>(inv, NN);

        gemm_k<128, false, false><<<GEMM_BLOCKS, 256, 0, stream>>>(x, wn0, nullptr, Bf);
        gemm_k<128, false, true ><<<GEMM_BLOCKS, 256, 0, stream>>>(x, ws0, b0, H0);
        scatter128_k<<<SC_BLOCKS, 256, 0, stream>>>(src, dst, inv, Bf, H0, NE);
        gemm_k<128, true, false><<<GEMM_BLOCKS, 256, 0, stream>>>(H0, wn1, nullptr, Bf);
        gemm_k<128, true, true ><<<GEMM_BLOCKS, 256, 0, stream>>>(H0, ws1, b1, H0);
        scatter128_k<<<SC_BLOCKS, 256, 0, stream>>>(src, dst, inv, Bf, H0, NE);
        gemm_k<64, true, false><<<GEMM_BLOCKS, 256, 0, stream>>>(H0, wn2, nullptr, Bf);
        gemm_k<64, true, true ><<<GEMM_BLOCKS, 256, 0, stream>>>(H0, ws2, b2, out);
        scatter64_k<<<SC_BLOCKS, 256, 0, stream>>>(src, dst, inv, Bf, out, NE);
    }
}

// Round 3
// 634.300 us; speedup vs baseline: 5.5264x; 1.5488x over previous
//
#include <hip/hip_runtime.h>

// GraphSAGE 3-layer forward. R3: bf16 MFMA fused GEMMs + bf16 gather table.
// Per layer: [A | Bt] = H @ [Ws|Wn]  (one fused MFMA GEMM, A fp32 + bias, Bt bf16)
//            Hnext = relu(A + mean_{e:dst=d} Bt[src[e]])  stored bf16 (layer2: no relu, fp32 out)
// CSR(by-dst) rebuilt every call. All accumulation fp32.

#define NN 100000
#define NE 1600000

typedef __attribute__((ext_vector_type(8))) short short8;
typedef __attribute__((ext_vector_type(4))) float f32x4;
typedef unsigned int uint;
typedef unsigned short ushort;

__device__ inline ushort f2bf(float f) {
    uint u = __float_as_uint(f);
    u += 0x7FFFu + ((u >> 16) & 1u);
    return (ushort)(u >> 16);
}
__device__ inline float bf_lo(uint w) { return __uint_as_float(w << 16); }
__device__ inline float bf_hi(uint w) { return __uint_as_float(w & 0xFFFF0000u); }

// ---------------- CSR build ----------------
__global__ void hist_k(const int* __restrict__ dst, int* __restrict__ cnt, int E) {
    const int i = blockIdx.x * blockDim.x + threadIdx.x;
    if (i < E) atomicAdd(&cnt[dst[i]], 1);
}

__global__ __launch_bounds__(256) void scan1_k(const int* __restrict__ cnt,
                                               int* __restrict__ row, int* __restrict__ blksum) {
    __shared__ int lds[256];
    const int t = threadIdx.x;
    const int base = blockIdx.x * 1024 + t * 4;
    int v[4];
    #pragma unroll
    for (int i = 0; i < 4; ++i) {
        const int idx = base + i;
        v[i] = (idx < NN) ? cnt[idx] : 0;
    }
    const int s = v[0] + v[1] + v[2] + v[3];
    lds[t] = s;
    __syncthreads();
    #pragma unroll
    for (int off = 1; off < 256; off <<= 1) {
        const int cur = lds[t];
        const int y = (t >= off) ? lds[t - off] : 0;
        __syncthreads();
        lds[t] = cur + y;
        __syncthreads();
    }
    const int incl = lds[t];
    if (t == 255) blksum[blockIdx.x] = incl;
    int run = incl - s;
    #pragma unroll
    for (int i = 0; i < 4; ++i) {
        const int idx = base + i;
        if (idx < NN) row[idx] = run;
        run += v[i];
    }
}

__global__ __launch_bounds__(128) void scan2_k(int* blksum, int nb) {
    __shared__ int lds[128];
    const int t = threadIdx.x;
    const int s = (t < nb) ? blksum[t] : 0;
    lds[t] = s;
    __syncthreads();
    #pragma unroll
    for (int off = 1; off < 128; off <<= 1) {
        const int cur = lds[t];
        const int y = (t >= off) ? lds[t - off] : 0;
        __syncthreads();
        lds[t] = cur + y;
        __syncthreads();
    }
    if (t < nb) blksum[t] = lds[t] - s;
}

__global__ __launch_bounds__(256) void scan3_k(int* __restrict__ row, const int* __restrict__ blksum) {
    const int t = threadIdx.x;
    const int add = blksum[blockIdx.x];
    const int base = blockIdx.x * 1024 + t * 4;
    #pragma unroll
    for (int i = 0; i < 4; ++i) {
        const int idx = base + i;
        if (idx < NN) row[idx] += add;
    }
    if (blockIdx.x == 0 && t == 0) row[NN] = NE;
}

__global__ void place_k(const int* __restrict__ src, const int* __restrict__ dst,
                        const int* __restrict__ row, int* __restrict__ cnt,
                        int* __restrict__ esrc, int E) {
    const int e = blockIdx.x * blockDim.x + threadIdx.x;
    if (e < E) {
        const int d = dst[e];
        const int r = atomicSub(&cnt[d], 1) - 1;
        esrc[row[d] + r] = src[e];
    }
}

// ---------------- fp32 -> bf16 feature convert (x -> Hb) ----------------
__global__ __launch_bounds__(256) void cvt_x_k(const float* __restrict__ x, ushort* __restrict__ hb) {
    const int idx = blockIdx.x * 256 + threadIdx.x;       // one per 8 elems
    if (idx >= NN * 16) return;
    const float4* xp = (const float4*)x;
    const float4 a = xp[idx * 2];
    const float4 b = xp[idx * 2 + 1];
    uint4 o;
    o.x = (uint)f2bf(a.x) | ((uint)f2bf(a.y) << 16);
    o.y = (uint)f2bf(a.z) | ((uint)f2bf(a.w) << 16);
    o.z = (uint)f2bf(b.x) | ((uint)f2bf(b.y) << 16);
    o.w = (uint)f2bf(b.z) | ((uint)f2bf(b.w) << 16);
    ((uint4*)hb)[idx] = o;
}

// ---------------- weight pack: [Ws|Wn] fp32 -> bf16 B-fragment-major ----------------
// frag f = ct*4+kt ; within frag, lane l holds B[k=kt*32+(l>>4)*8+j][n=ct*16+(l&15)], j=0..7
template<int NCS, int NCN>
__global__ __launch_bounds__(256) void pack_w_k(const float* __restrict__ ws, const float* __restrict__ wn,
                                                ushort* __restrict__ wf) {
    constexpr int TOTAL = ((NCS + NCN) / 16) * 4 * 64;
    const int idx = blockIdx.x * 256 + threadIdx.x;
    if (idx >= TOTAL) return;
    const int l = idx & 63;
    const int f = idx >> 6;
    const int kt = f & 3;
    const int ct = f >> 2;
    const int n = ct * 16 + (l & 15);
    const int k0 = kt * 32 + (l >> 4) * 8;
    uint w[4];
    #pragma unroll
    for (int p = 0; p < 4; ++p) {
        const int k = k0 + p * 2;
        float v0, v1;
        if (n < NCS) { v0 = ws[k * NCS + n];        v1 = ws[(k + 1) * NCS + n]; }
        else         { v0 = wn[k * NCN + (n - NCS)]; v1 = wn[(k + 1) * NCN + (n - NCS)]; }
        w[p] = (uint)f2bf(v0) | ((uint)f2bf(v1) << 16);
    }
    uint4 o; o.x = w[0]; o.y = w[1]; o.z = w[2]; o.w = w[3];
    ((uint4*)wf)[idx] = o;
}

// ---------------- fused MFMA GEMM: [A | Bt] = H @ Wcat ----------------
// wave per 16-row group; A-frags straight from global H (bf16); W-frags from
// packed global (L2-hot). C/D: col=lane&15, row=(lane>>4)*4+reg.
template<int NCS, int NCN>
__global__ __launch_bounds__(256) void gemm_mfma_k(
    const ushort* __restrict__ H, const ushort* __restrict__ Wf,
    const float* __restrict__ bias, float* __restrict__ A, ushort* __restrict__ Bt)
{
    constexpr int NCT = (NCS + NCN) / 16;
    const int g = (blockIdx.x * 256 + threadIdx.x) >> 6;
    if (g >= NN / 16) return;               // wave-uniform exit
    const int lane = threadIdx.x & 63;
    const int m = lane & 15;
    const int q = lane >> 4;

    const short8* hp = (const short8*)(H + (size_t)(g * 16 + m) * 128);
    short8 af[4];
    #pragma unroll
    for (int kt = 0; kt < 4; ++kt) af[kt] = hp[kt * 4 + q];   // 16B @ k=kt*32+q*8

    f32x4 acc[NCT];
    #pragma unroll
    for (int i = 0; i < NCT; ++i) acc[i] = (f32x4){0.f, 0.f, 0.f, 0.f};

    const short8* wp = (const short8*)Wf;
    #pragma unroll
    for (int ct = 0; ct < NCT; ++ct) {
        #pragma unroll
        for (int kt = 0; kt < 4; ++kt) {
            const short8 bf = wp[(ct * 4 + kt) * 64 + lane];
            acc[ct] = __builtin_amdgcn_mfma_f32_16x16x32_bf16(af[kt], bf, acc[ct], 0, 0, 0);
        }
    }

    const int r0 = g * 16 + q * 4;
    #pragma unroll
    for (int ct = 0; ct < NCS / 16; ++ct) {
        const int c = ct * 16 + m;
        const float bv = bias[c];
        #pragma unroll
        for (int r = 0; r < 4; ++r)
            A[(size_t)(r0 + r) * NCS + c] = acc[ct][r] + bv;
    }
    #pragma unroll
    for (int ct = NCS / 16; ct < NCT; ++ct) {
        const int c = ct * 16 + m - NCS;
        #pragma unroll
        for (int r = 0; r < 4; ++r)
            Bt[(size_t)(r0 + r) * NCN + c] = f2bf(acc[ct][r]);
    }
}

// ---------------- aggregation ----------------
// wave per node: Hb[node] = relu(A[node] + mean(Bt[src])) as bf16
template<bool RELU>
__global__ __launch_bounds__(256) void agg128_k(
    const int* __restrict__ row, const int* __restrict__ esrc,
    const ushort* __restrict__ Bt, const float* __restrict__ A, ushort* __restrict__ Hb)
{
    const int node = (blockIdx.x * 256 + threadIdx.x) >> 6;
    if (node >= NN) return;
    const int lane = threadIdx.x & 63;
    const int e0 = row[node];
    const int e1 = row[node + 1];
    const uint* B32 = (const uint*)Bt;
    float a0 = 0.f, a1 = 0.f;
    int e = e0;
    for (; e + 4 <= e1; e += 4) {
        const int s0 = esrc[e], s1 = esrc[e + 1], s2 = esrc[e + 2], s3 = esrc[e + 3];
        const uint w0 = B32[(size_t)s0 * 64 + lane];
        const uint w1 = B32[(size_t)s1 * 64 + lane];
        const uint w2 = B32[(size_t)s2 * 64 + lane];
        const uint w3 = B32[(size_t)s3 * 64 + lane];
        a0 += (bf_lo(w0) + bf_lo(w1)) + (bf_lo(w2) + bf_lo(w3));
        a1 += (bf_hi(w0) + bf_hi(w1)) + (bf_hi(w2) + bf_hi(w3));
    }
    for (; e < e1; ++e) {
        const uint w = B32[(size_t)esrc[e] * 64 + lane];
        a0 += bf_lo(w);
        a1 += bf_hi(w);
    }
    const float invd = (e1 > e0) ? 1.0f / (float)(e1 - e0) : 0.0f;
    const float2 av = *(const float2*)(A + (size_t)node * 128 + lane * 2);
    float v0 = av.x + a0 * invd;
    float v1 = av.y + a1 * invd;
    if (RELU) { v0 = fmaxf(v0, 0.f); v1 = fmaxf(v1, 0.f); }
    ((uint*)Hb)[(size_t)node * 64 + lane] = (uint)f2bf(v0) | ((uint)f2bf(v1) << 16);
}

// layer 2: out[node] += mean(Bt64[src]) (fp32 in place, no relu)
__global__ __launch_bounds__(256) void agg64_k(
    const int* __restrict__ row, const int* __restrict__ esrc,
    const ushort* __restrict__ Bt, float* __restrict__ out)
{
    const int node = (blockIdx.x * 256 + threadIdx.x) >> 6;
    if (node >= NN) return;
    const int lane = threadIdx.x & 63;
    const int e0 = row[node];
    const int e1 = row[node + 1];
    float a = 0.f;
    int e = e0;
    for (; e + 4 <= e1; e += 4) {
        const int s0 = esrc[e], s1 = esrc[e + 1], s2 = esrc[e + 2], s3 = esrc[e + 3];
        const float f0 = __uint_as_float((uint)Bt[(size_t)s0 * 64 + lane] << 16);
        const float f1 = __uint_as_float((uint)Bt[(size_t)s1 * 64 + lane] << 16);
        const float f2 = __uint_as_float((uint)Bt[(size_t)s2 * 64 + lane] << 16);
        const float f3 = __uint_as_float((uint)Bt[(size_t)s3 * 64 + lane] << 16);
        a += (f0 + f1) + (f2 + f3);
    }
    for (; e < e1; ++e)
        a += __uint_as_float((uint)Bt[(size_t)esrc[e] * 64 + lane] << 16);
    const float invd = (e1 > e0) ? 1.0f / (float)(e1 - e0) : 0.0f;
    out[(size_t)node * 64 + lane] += a * invd;
}

// ---------------- fp32 fallback path (small workspace) ----------------
__device__ inline float4 relu4f(float4 v) {
    v.x = fmaxf(v.x, 0.f); v.y = fmaxf(v.y, 0.f);
    v.z = fmaxf(v.z, 0.f); v.w = fmaxf(v.w, 0.f);
    return v;
}
template<int NCOL, bool RELU_IN, bool BIAS>
__global__ __launch_bounds__(256) void gemm_k(
    const float* in, const float* __restrict__ W,
    const float* __restrict__ bias, float* out)
{
    constexpr int K = 128;
    constexpr int QUADS = NCOL / 4;
    constexpr int G = 256 / QUADS;
    constexpr int RPT = 32 / G;
    __shared__ float Wlds[K * NCOL];
    {
        const float4* Wg = reinterpret_cast<const float4*>(W);
        float4* Wl = reinterpret_cast<float4*>(Wlds);
        #pragma unroll
        for (int i = 0; i < K * NCOL / 4 / 256; ++i)
            Wl[threadIdx.x + i * 256] = Wg[threadIdx.x + i * 256];
    }
    __syncthreads();
    const int tx = threadIdx.x % QUADS;
    const int ty = threadIdx.x / QUADS;
    const int row0 = blockIdx.x * 32;
    const float* rp[RPT];
    #pragma unroll
    for (int i = 0; i < RPT; ++i) rp[i] = in + (size_t)(row0 + ty + i * G) * K;
    float acc[RPT][4];
    #pragma unroll
    for (int i = 0; i < RPT; ++i) acc[i][0] = acc[i][1] = acc[i][2] = acc[i][3] = 0.f;
    #pragma unroll 2
    for (int kc = 0; kc < K; kc += 4) {
        float4 h4[RPT];
        #pragma unroll
        for (int i = 0; i < RPT; ++i) {
            h4[i] = *reinterpret_cast<const float4*>(rp[i] + kc);
            if (RELU_IN) h4[i] = relu4f(h4[i]);
        }
        #pragma unroll
        for (int kk = 0; kk < 4; ++kk) {
            const float4 w4 = *reinterpret_cast<const float4*>(&Wlds[(kc + kk) * NCOL + tx * 4]);
            #pragma unroll
            for (int i = 0; i < RPT; ++i) {
                const float hv = (&h4[i].x)[kk];
                acc[i][0] = fmaf(hv, w4.x, acc[i][0]);
                acc[i][1] = fmaf(hv, w4.y, acc[i][1]);
                acc[i][2] = fmaf(hv, w4.z, acc[i][2]);
                acc[i][3] = fmaf(hv, w4.w, acc[i][3]);
            }
        }
    }
    float4 b4 = make_float4(0.f, 0.f, 0.f, 0.f);
    if (BIAS) b4 = *reinterpret_cast<const float4*>(&bias[tx * 4]);
    #pragma unroll
    for (int i = 0; i < RPT; ++i) {
        const int r = row0 + ty + i * G;
        float4 o;
        o.x = acc[i][0] + b4.x; o.y = acc[i][1] + b4.y;
        o.z = acc[i][2] + b4.z; o.w = acc[i][3] + b4.w;
        *reinterpret_cast<float4*>(&out[(size_t)r * NCOL + tx * 4]) = o;
    }
}
__global__ void deg_k(const int* __restrict__ dst, float* __restrict__ deg, int E) {
    const int i = blockIdx.x * blockDim.x + threadIdx.x;
    if (i < E) atomicAdd(&deg[dst[i]], 1.0f);
}
__global__ void inv_k(float* deg, int n) {
    const int i = blockIdx.x * blockDim.x + threadIdx.x;
    if (i < n) deg[i] = 1.0f / fmaxf(deg[i], 1.0f);
}
__global__ __launch_bounds__(256) void scatter128_k(
    const int* __restrict__ src, const int* __restrict__ dst,
    const float* __restrict__ inv, const float* __restrict__ B, float* A, int E) {
    const int lane = threadIdx.x & 63;
    int w = (blockIdx.x * 256 + threadIdx.x) >> 6;
    const int nw = (gridDim.x * 256) >> 6;
    for (int e = w; e < E; e += nw) {
        const int s = src[e], d = dst[e];
        const float sc = inv[d];
        const float2 v = *reinterpret_cast<const float2*>(&B[(size_t)s * 128 + lane * 2]);
        atomicAdd(&A[(size_t)d * 128 + lane * 2    ], v.x * sc);
        atomicAdd(&A[(size_t)d * 128 + lane * 2 + 1], v.y * sc);
    }
}
__global__ __launch_bounds__(256) void scatter64_k(
    const int* __restrict__ src, const int* __restrict__ dst,
    const float* __restrict__ inv, const float* __restrict__ B, float* A, int E) {
    const int lane = threadIdx.x & 63;
    int w = (blockIdx.x * 256 + threadIdx.x) >> 6;
    const int nw = (gridDim.x * 256) >> 6;
    for (int e = w; e < E; e += nw) {
        const int s = src[e], d = dst[e];
        atomicAdd(&A[(size_t)d * 64 + lane], B[(size_t)s * 64 + lane] * inv[d]);
    }
}

extern "C" void kernel_launch(void* const* d_in, const int* in_sizes, int n_in,
                              void* d_out, int out_size, void* d_ws, size_t ws_size,
                              hipStream_t stream) {
    const float* x   = (const float*)d_in[0];
    const int*   src = (const int*)  d_in[1];
    const int*   dst = (const int*)  d_in[2];
    const float* ws0 = (const float*)d_in[3];
    const float* wn0 = (const float*)d_in[4];
    const float* b0  = (const float*)d_in[5];
    const float* ws1 = (const float*)d_in[6];
    const float* wn1 = (const float*)d_in[7];
    const float* b1  = (const float*)d_in[8];
    const float* ws2 = (const float*)d_in[9];
    const float* wn2 = (const float*)d_in[10];
    const float* b2  = (const float*)d_in[11];
    float* out = (float*)d_out;

    // workspace layout (byte offsets, all 16B-aligned where vectorized)
    const size_t O_CNT  = 0;          // 400000
    const size_t O_ROW  = 400384;     // 400004
    const size_t O_BLK  = 800512;     // 512
    const size_t O_WF0  = 801024;     // 65536
    const size_t O_WF1  = 866560;     // 65536
    const size_t O_WF2  = 932096;     // 32768
    const size_t O_ESRC = 964864;     // 6400000
    const size_t O_A    = 7364864;    // 51200000
    const size_t O_BT   = 58564864;   // 25600000
    const size_t O_HB   = 84164864;   // 25600000
    const size_t NEED   = 109764864;

    const int NBLK = (NN + 1023) / 1024;   // 98

    if (ws_size >= NEED) {
        int*    cnt  = (int*)   ((char*)d_ws + O_CNT);
        int*    row  = (int*)   ((char*)d_ws + O_ROW);
        int*    blks = (int*)   ((char*)d_ws + O_BLK);
        ushort* wf0  = (ushort*)((char*)d_ws + O_WF0);
        ushort* wf1  = (ushort*)((char*)d_ws + O_WF1);
        ushort* wf2  = (ushort*)((char*)d_ws + O_WF2);
        int*    esrc = (int*)   ((char*)d_ws + O_ESRC);
        float*  A    = (float*) ((char*)d_ws + O_A);
        ushort* Bt   = (ushort*)((char*)d_ws + O_BT);
        ushort* Hb   = (ushort*)((char*)d_ws + O_HB);

        // CSR build
        hipMemsetAsync(cnt, 0, NN * sizeof(int), stream);
        hist_k<<<(NE + 255) / 256, 256, 0, stream>>>(dst, cnt, NE);
        scan1_k<<<NBLK, 256, 0, stream>>>(cnt, row, blks);
        scan2_k<<<1, 128, 0, stream>>>(blks, NBLK);
        scan3_k<<<NBLK, 256, 0, stream>>>(row, blks);
        place_k<<<(NE + 255) / 256, 256, 0, stream>>>(src, dst, row, cnt, esrc, NE);

        // weight packs + x cast
        pack_w_k<128, 128><<<16, 256, 0, stream>>>(ws0, wn0, wf0);
        pack_w_k<128, 128><<<16, 256, 0, stream>>>(ws1, wn1, wf1);
        pack_w_k< 64,  64><<< 8, 256, 0, stream>>>(ws2, wn2, wf2);
        cvt_x_k<<<(NN * 16 + 255) / 256, 256, 0, stream>>>(x, Hb);

        const int GEMM_BLOCKS = (NN / 16 + 3) / 4;   // 1563 (4 waves/block)
        const int AGG_BLOCKS  = (NN + 3) / 4;        // 25000

        // layer 0
        gemm_mfma_k<128, 128><<<GEMM_BLOCKS, 256, 0, stream>>>(Hb, wf0, b0, A, Bt);
        agg128_k<true><<<AGG_BLOCKS, 256, 0, stream>>>(row, esrc, Bt, A, Hb);
        // layer 1
        gemm_mfma_k<128, 128><<<GEMM_BLOCKS, 256, 0, stream>>>(Hb, wf1, b1, A, Bt);
        agg128_k<true><<<AGG_BLOCKS, 256, 0, stream>>>(row, esrc, Bt, A, Hb);
        // layer 2 (self straight to d_out, fp32; then in-place mean add)
        gemm_mfma_k<64, 64><<<GEMM_BLOCKS, 256, 0, stream>>>(Hb, wf2, b2, out, Bt);
        agg64_k<<<AGG_BLOCKS, 256, 0, stream>>>(row, esrc, Bt, out);
    } else {
        // fp32 atomic fallback
        float* inv = (float*)d_ws;
        float* H0  = (float*)((char*)d_ws + (1u << 20));
        float* Bf  = H0 + (size_t)NN * 128;
        const int GEMM_BLOCKS = NN / 32;
        const int SC_BLOCKS = 4096;
        hipMemsetAsync(inv, 0, NN * sizeof(float), stream);
        deg_k<<<(NE + 255) / 256, 256, 0, stream>>>(dst, inv, NE);
        inv_k<<<(NN + 255) / 256, 256, 0, stream>>>(inv, NN);
        gemm_k<128, false, false><<<GEMM_BLOCKS, 256, 0, stream>>>(x, wn0, nullptr, Bf);
        gemm_k<128, false, true ><<<GEMM_BLOCKS, 256, 0, stream>>>(x, ws0, b0, H0);
        scatter128_k<<<SC_BLOCKS, 256, 0, stream>>>(src, dst, inv, Bf, H0, NE);
        gemm_k<128, true, false><<<GEMM_BLOCKS, 256, 0, stream>>>(H0, wn1, nullptr, Bf);
        gemm_k<128, true, true ><<<GEMM_BLOCKS, 256, 0, stream>>>(H0, ws1, b1, H0);
        scatter128_k<<<SC_BLOCKS, 256, 0, stream>>>(src, dst, inv, Bf, H0, NE);
        gemm_k<64, true, false><<<GEMM_BLOCKS, 256, 0, stream>>>(H0, wn2, nullptr, Bf);
        gemm_k<64, true, true ><<<GEMM_BLOCKS, 256, 0, stream>>>(H0, ws2, b2, out);
        scatter64_k<<<SC_BLOCKS, 256, 0, stream>>>(src, dst, inv, Bf, out, NE);
    }
}